// Round 3
// baseline (85.306 us; speedup 1.0000x reference)
//
#include <hip/hip_runtime.h>

typedef float fx4 __attribute__((ext_vector_type(4)));   // native vec type for nt-store

// Fast 8-point DCT-II (unnormalized: o[u] = sum_x a[x]*cos((2x+1)u*pi/16)),
// even/odd factored: ~35 VALU ops vs 64 FMA direct. All coefficients literal.
__device__ __forceinline__ void dct8(const float a[8], float o[8]) {
    const float s0 = a[0] + a[7], s1 = a[1] + a[6], s2 = a[2] + a[5], s3 = a[3] + a[4];
    const float d0 = a[0] - a[7], d1 = a[1] - a[6], d2 = a[2] - a[5], d3 = a[3] - a[4];
    const float ss0 = s0 + s3, ss1 = s1 + s2;
    const float ds0 = s0 - s3, ds1 = s1 - s2;
    o[0] = ss0 + ss1;
    o[4] = 0.70710678f * (ss0 - ss1);
    o[2] = fmaf(0.92387953f, ds0,  0.38268343f * ds1);
    o[6] = fmaf(0.38268343f, ds0, -0.92387953f * ds1);
    o[1] = fmaf(0.98078528f, d0, fmaf( 0.83146961f, d1, fmaf( 0.55557023f, d2,  0.19509032f * d3)));
    o[3] = fmaf(0.83146961f, d0, fmaf(-0.19509032f, d1, fmaf(-0.98078528f, d2, -0.55557023f * d3)));
    o[5] = fmaf(0.55557023f, d0, fmaf(-0.98078528f, d1, fmaf( 0.19509032f, d2,  0.83146961f * d3)));
    o[7] = fmaf(0.19509032f, d0, fmaf(-0.55557023f, d1, fmaf( 0.83146961f, d2, -0.98078528f * d3)));
}

// 8 lanes per 8x8 block. Lane c:
//   pass 1: load column c (8 strided dwords), fast DCT over x  -> B[u][c]
//   transpose via padded LDS (2-way bank aliasing = free)
//   pass 2: fast DCT over y on row c of B -> output row c, coalesced nt-stores.
__global__ __launch_bounds__(256) void dct8x8_kernel(const float* __restrict__ in,
                                                     float* __restrict__ out,
                                                     int nthreads) {
    __shared__ float lds[256 * 9];   // pad 8 -> 9 words per lane-row

    int tid = blockIdx.x * 256 + threadIdx.x;
    if (tid >= nthreads) tid = nthreads - 1;   // grid divides exactly in practice
    const int lane = threadIdx.x;
    const int c = lane & 7;                    // column for pass 1 == output row for pass 2
    const size_t blk = (size_t)(tid >> 3);

    // ---- pass 1: load column c of the block, DCT over x ----
    const float* bp = in + blk * 64 + c;
    float a[8];
#pragma unroll
    for (int x = 0; x < 8; ++x) a[x] = bp[x * 8];

    float B[8];
    dct8(a, B);
    B[0] -= 1024.0f;   // the global -128 shift only affects the DC term (8*128)

    // ---- transpose within the 8-lane group via LDS ----
#pragma unroll
    for (int u = 0; u < 8; ++u) lds[lane * 9 + u] = B[u];
    __syncthreads();

    const int gbase = (lane & ~7) * 9;
    float t[8];
#pragma unroll
    for (int y = 0; y < 8; ++y) t[y] = lds[gbase + y * 9 + c];

    // ---- pass 2: DCT over y -> output row c ----
    float o[8];
    dct8(t, o);

    // ---- scale[u][v] = (0.5*alpha_u)(0.5*alpha_v) ----
    const float su = (c == 0) ? 0.35355339059f : 0.5f;
#pragma unroll
    for (int v = 0; v < 8; ++v) o[v] *= su * ((v == 0) ? 0.35355339059f : 0.5f);

    // ---- coalesced nontemporal stores (don't evict the L3-resident input) ----
    fx4 q0 = { o[0], o[1], o[2], o[3] };
    fx4 q1 = { o[4], o[5], o[6], o[7] };
    fx4* qp = reinterpret_cast<fx4*>(out) + (size_t)tid * 2;
    __builtin_nontemporal_store(q0, qp);
    __builtin_nontemporal_store(q1, qp + 1);
}

extern "C" void kernel_launch(void* const* d_in, const int* in_sizes, int n_in,
                              void* d_out, int out_size, void* d_ws, size_t ws_size,
                              hipStream_t stream) {
    const float* in = (const float*)d_in[0];
    float* out = (float*)d_out;
    const int n = in_sizes[0];          // 64*3*4096*64 = 50,331,648 floats
    const int nthreads = n / 8;         // one lane per block-column/row
    const int grid = (nthreads + 255) / 256;
    hipLaunchKernelGGL(dct8x8_kernel, dim3(grid), dim3(256), 0, stream,
                       in, out, nthreads);
}